// Round 12
// baseline (369.801 us; speedup 1.0000x reference)
//
#include <hip/hip_runtime.h>

#define G_TOT 2016
#define NGB32 63
#define HSTR 40   // hbuf row stride in f16 (80B): fragment-contiguous, 2-way banks
#define CSTR 33   // cob row stride (f32)

typedef _Float16 f16;
typedef __attribute__((ext_vector_type(2))) _Float16 v2h;
typedef __attribute__((ext_vector_type(8))) _Float16 v8h;
typedef __attribute__((ext_vector_type(4))) float v4f;

__device__ __forceinline__ v2h pkrtz(float a, float b) {
    return __builtin_bit_cast(v2h, __builtin_amdgcn_cvt_pkrtz(a, b));
}

// ---------------------------------------------------------------------------
// Prep: gather Y into x32-MFMA-fragment-ordered f16 tables (per 32-g block).
// ---------------------------------------------------------------------------
__global__ void vg_prep(const float* __restrict__ Y, const float* __restrict__ qw,
                        f16* __restrict__ A1buf, f16* __restrict__ B2buf) {
    const int gb = blockIdx.x;
    const int lane = threadIdx.x & 63;
    const int lhi = lane >> 4, llo = lane & 15;
#pragma unroll
    for (int gh = 0; gh < 2; ++gh) {
        const int g = gb * 32 + gh * 16 + llo;
#pragma unroll
        for (int j = 0; j < 8; ++j) {
            const int k = (j < 4) ? (lhi * 4 + j) : (16 + lhi * 4 + (j - 4));
            const float v = (k < 25) ? Y[k * G_TOT + g] : 0.0f;
            A1buf[((gb * 2 + gh) * 64 + lane) * 8 + j] = (f16)v;
        }
    }
#pragma unroll
    for (int t = 0; t < 2; ++t) {
        const int k = t * 16 + llo;
#pragma unroll
        for (int j = 0; j < 8; ++j) {
            const int g = gb * 32 + ((j < 4) ? (lhi * 4 + j) : (16 + lhi * 4 + (j - 4)));
            const float v = (k < 25) ? Y[k * G_TOT + g] * qw[g] : 0.0f;
            B2buf[((gb * 2 + t) * 64 + lane) * 8 + j] = (f16)v;
        }
    }
}

// ---------------------------------------------------------------------------
// Main fused kernel: 256 threads per (n, parity); waves = (h = c-half, q = g-half).
// Phase 0b: MFMA channel mix on all 4 waves (wave = (s, ct) quarter).
// Main loop: SOFTWARE-PIPELINED — iteration issues MFMA1 for body i+1 into agB
// BEFORE finishing body i (cross+MFMA2 from agA); sched_barrier(0) pins the
// order so cross never waits on freshly-issued MFMAs (R10 showed VGPR=64 =>
// compiler serialized bodies; this forces cross-body overlap).
// ---------------------------------------------------------------------------
template <bool USE_WS>
__global__ __launch_bounds__(256, 3)
void vg_main(const float* __restrict__ x1, const float* __restrict__ x2,
             const float* __restrict__ W1s, const float* __restrict__ W2s,
             const float* __restrict__ Wouts, const float* __restrict__ Y,
             const float* __restrict__ qw,
             const f16* __restrict__ A1buf, const f16* __restrict__ B2buf,
             float* __restrict__ out) {
    __shared__ __align__(16) char smem[15360];
    f16* hb = (f16*)smem;        // [2][96][HSTR] f16, fragment layout (phase 0)
    float* cob = (float*)smem;   // [96][CSTR] f32 (reduce/epilogue; aliased)

    const int bid = blockIdx.x;
    const int n = bid / 3, p = bid % 3;
    const int tid = threadIdx.x;
    const int wid = tid >> 6;
    const int h = wid & 1;       // c-half owned (main loop)
    const int q = wid >> 1;      // g-split (main loop)
    const int lane = tid & 63;
    const int lhi = lane >> 4, llo = lane & 15;

    const v4f zero4 = {0.0f, 0.0f, 0.0f, 0.0f};

    // ---- phase 0a: zero hb (padding slots must be 0)
    for (int i = tid; i < 3840; i += 256) ((float*)smem)[i] = 0.0f;
    __syncthreads();

    // ---- phase 0b (MFMA, all 4 waves): wave (s, ct) computes its quarter.
    {
        const int s = wid & 1, ct = wid >> 1;
        const float* xs = (s ? x2 : x1) + n * 2400;
        const float* Wp = (s ? W2s : W1s) + p * 5120;
        v8h bf[5];
#pragma unroll
        for (int l = 0; l < 5; ++l)
#pragma unroll
            for (int j = 0; j < 8; ++j) {
                const int f = (j < 4) ? (lhi * 4 + j) : (16 + lhi * 4 + (j - 4));
                bf[l][j] = (f16)Wp[l * 1024 + f * 32 + ct * 16 + llo];
            }
        f16* hbs = hb + s * 96 * HSTR;
#pragma unroll
        for (int vt = 0; vt < 5; ++vt) {
            v8h af;
            const int vkb = vt * 16 + llo;
#pragma unroll
            for (int j = 0; j < 8; ++j) {
                const int f = (j < 4) ? (lhi * 4 + j) : (16 + lhi * 4 + (j - 4));
                af[j] = (vkb < 75) ? (f16)xs[f * 75 + vkb] : (f16)0.0f;
            }
            v4f D[5];
#pragma unroll
            for (int l = 0; l < 5; ++l)
                D[l] = __builtin_amdgcn_mfma_f32_16x16x32_f16(af, bf[l], zero4, 0, 0, 0);
#pragma unroll
            for (int j = 0; j < 4; ++j) {
                const int vk = vt * 16 + lhi * 4 + j;
                if (vk < 75) {
                    const int v = (vk >= 50) ? 2 : ((vk >= 25) ? 1 : 0);
                    const int k = vk - v * 25;
                    const float val = (k < 1) ? D[0][j]
                                    : (k < 4) ? D[1][j]
                                    : (k < 9) ? D[2][j]
                                    : (k < 16) ? D[3][j]
                                    : D[4][j];
                    const int ks = (k < 16) ? ((k >> 2) * 8 + (k & 3))
                                           : (((k - 16) >> 2) * 8 + 4 + ((k - 16) & 3));
                    hbs[(v * 32 + ct * 16 + llo) * HSTR + ks] = (f16)val;
                }
            }
        }
    }
    __syncthreads();

    // ---- hoist this wave's h fragments: tiles Rn = 2*vc + h (6 x v8h = 24 VGPR)
    v8h hfr[2][3];
    {
        const f16* hfb = &hb[llo * HSTR + lhi * 8];
#pragma unroll
        for (int s = 0; s < 2; ++s)
#pragma unroll
            for (int vc = 0; vc < 3; ++vc)
                hfr[s][vc] = *(const v8h*)(hfb + (s * 96 + (2 * vc + h) * 16) * HSTR);
    }

    v4f coacc[3][2];
#pragma unroll
    for (int vc = 0; vc < 3; ++vc)
#pragma unroll
        for (int t = 0; t < 2; ++t) coacc[vc][t] = zero4;

    union A2U { v2h p[4]; v8h v; };

    // MFMA1 cluster for one body: 12 MFMAs into ag[2][3]
    auto mfma1 = [&](const v8h& a1lo, const v8h& a1hi, v4f (&ag)[2][2][3]) {
#pragma unroll
        for (int gh = 0; gh < 2; ++gh) {
            const v8h a1 = gh ? a1hi : a1lo;
#pragma unroll
            for (int s = 0; s < 2; ++s)
#pragma unroll
                for (int vc = 0; vc < 3; ++vc)
                    ag[gh][s][vc] = __builtin_amdgcn_mfma_f32_16x16x32_f16(
                        a1, hfr[s][vc], zero4, 0, 0, 0);
        }
    };

    // finish one body: packed-f16 cross + MFMA2 accumulate
    auto finish = [&](const v4f (&ag)[2][2][3], const v8h& b2lo, const v8h& b2hi) {
        A2U a2u[3];
#pragma unroll
        for (int gh = 0; gh < 2; ++gh) {
            v2h g1[3][2], g2[3][2];
#pragma unroll
            for (int vc = 0; vc < 3; ++vc) {
                g1[vc][0] = pkrtz(ag[gh][0][vc][0], ag[gh][0][vc][1]);
                g1[vc][1] = pkrtz(ag[gh][0][vc][2], ag[gh][0][vc][3]);
                g2[vc][0] = pkrtz(ag[gh][1][vc][0], ag[gh][1][vc][1]);
                g2[vc][1] = pkrtz(ag[gh][1][vc][2], ag[gh][1][vc][3]);
            }
#pragma unroll
            for (int jp = 0; jp < 2; ++jp) {
                a2u[0].p[gh * 2 + jp] = g1[1][jp] * g2[2][jp] - g1[2][jp] * g2[1][jp];
                a2u[1].p[gh * 2 + jp] = g1[2][jp] * g2[0][jp] - g1[0][jp] * g2[2][jp];
                a2u[2].p[gh * 2 + jp] = g1[0][jp] * g2[1][jp] - g1[1][jp] * g2[0][jp];
            }
        }
#pragma unroll
        for (int vc = 0; vc < 3; ++vc) {
            coacc[vc][0] = __builtin_amdgcn_mfma_f32_16x16x32_f16(a2u[vc].v, b2lo, coacc[vc][0], 0, 0, 0);
            coacc[vc][1] = __builtin_amdgcn_mfma_f32_16x16x32_f16(a2u[vc].v, b2hi, coacc[vc][1], 0, 0, 0);
        }
    };

    // ---- main loop: software-pipelined over bodies b (gb = q + 2b)
    if constexpr (USE_WS) {
        const v8h* base_a = (const v8h*)A1buf + lane;
        const v8h* base_b = (const v8h*)B2buf + lane;
        const int iters = (NGB32 - q + 1) >> 1;        // q=0:32, q=1:31
        auto offA = [&](int b) { return (b < iters) ? (q + 2 * b) * 128 : q * 128; };

        v8h FAe_lo, FAe_hi, FAo_lo, FAo_hi, FBe_lo, FBe_hi, FBo_lo, FBo_hi;
        v4f agA[2][2][3], agB[2][2][3];

        // prologue: bodies 0,1 frags; MFMA1(body 0); then FA_e <- A(2)
        { const v8h* pa = base_a + offA(0); FAe_lo = pa[0]; FAe_hi = pa[64]; }
        { const v8h* pa = base_a + offA(1); FAo_lo = pa[0]; FAo_hi = pa[64]; }
        { const v8h* pb = base_b + offA(0); FBe_lo = pb[0]; FBe_hi = pb[64]; }
        { const v8h* pb = base_b + offA(1); FBo_lo = pb[0]; FBo_hi = pb[64]; }
        mfma1(FAe_lo, FAe_hi, agA);
        { const v8h* pa = base_a + offA(2); FAe_lo = pa[0]; FAe_hi = pa[64]; }

        const int npairs = iters >> 1;
        for (int k = 0; k < npairs; ++k) {
            // start body 2k+1
            mfma1(FAo_lo, FAo_hi, agB);
            __builtin_amdgcn_sched_barrier(0);
            { const v8h* pa = base_a + offA(2 * k + 3); FAo_lo = pa[0]; FAo_hi = pa[64]; }
            // finish body 2k
            finish(agA, FBe_lo, FBe_hi);
            { const v8h* pb = base_b + offA(2 * k + 2); FBe_lo = pb[0]; FBe_hi = pb[64]; }
            // start body 2k+2
            mfma1(FAe_lo, FAe_hi, agA);
            __builtin_amdgcn_sched_barrier(0);
            { const v8h* pa = base_a + offA(2 * k + 4); FAe_lo = pa[0]; FAe_hi = pa[64]; }
            // finish body 2k+1
            finish(agB, FBo_lo, FBo_hi);
            { const v8h* pb = base_b + offA(2 * k + 3); FBo_lo = pb[0]; FBo_hi = pb[64]; }
        }
        if (iters & 1) finish(agA, FBe_lo, FBe_hi);   // last (even-indexed) body
    } else {
        for (int gb = q; gb < NGB32; gb += 2) {
            v8h b20, b21, a10, a11;
#pragma unroll
            for (int j = 0; j < 8; ++j) {
                const int gg = gb * 32 + ((j < 4) ? (lhi * 4 + j) : (16 + lhi * 4 + (j - 4)));
                const float qg = qw[gg];
                b20[j] = (f16)(Y[llo * G_TOT + gg] * qg);
                const int k1 = 16 + llo;
                b21[j] = (f16)((k1 < 25) ? Y[k1 * G_TOT + gg] * qg : 0.0f);
                const int k = (j < 4) ? (lhi * 4 + j) : (16 + lhi * 4 + (j - 4));
                a10[j] = (f16)((k < 25) ? Y[k * G_TOT + gb * 32 + llo] : 0.0f);
                a11[j] = (f16)((k < 25) ? Y[k * G_TOT + gb * 32 + 16 + llo] : 0.0f);
            }
            v4f ag[2][2][3];
            mfma1(a10, a11, ag);
            finish(ag, b20, b21);
        }
    }

    // ---- CO: q=0 writes, q=1 accumulates (waves own disjoint rows across h)
    __syncthreads();
    if (q == 0) {
#pragma unroll
        for (int vc = 0; vc < 3; ++vc)
#pragma unroll
            for (int t = 0; t < 2; ++t)
#pragma unroll
                for (int j = 0; j < 4; ++j) {
                    const int row = (2 * vc + h) * 16 + lhi * 4 + j;
                    cob[row * CSTR + t * 16 + llo] = coacc[vc][t][j];
                }
    }
    __syncthreads();
    if (q == 1) {
#pragma unroll
        for (int vc = 0; vc < 3; ++vc)
#pragma unroll
            for (int t = 0; t < 2; ++t)
#pragma unroll
                for (int j = 0; j < 4; ++j) {
                    const int row = (2 * vc + h) * 16 + lhi * 4 + j;
                    cob[row * CSTR + t * 16 + llo] += coacc[vc][t][j];
                }
    }
    __syncthreads();

    // ---- epilogue: out[n, p*32+b, v, k] = sum_a co[v*32+a][k] * Wout[p,l_k,a,b]
    const float* Wop = Wouts + p * 5120;
    float* outp = out + (n * 96 + p * 32) * 75;
    for (int idx = tid; idx < 300; idx += 256) {
        const int vk = idx % 75, qq = idx / 75;
        const int v = vk / 25, k = vk - v * 25;
        const int l = (k >= 16) ? 4 : (k >= 9) ? 3 : (k >= 4) ? 2 : (k >= 1) ? 1 : 0;
        const float* w = Wop + l * 1024 + qq * 8;
        float acc[8];
#pragma unroll
        for (int b = 0; b < 8; ++b) acc[b] = 0.0f;
        for (int a = 0; a < 32; ++a) {
            const float cv = cob[(v * 32 + a) * CSTR + k];
#pragma unroll
            for (int b = 0; b < 8; ++b) acc[b] += cv * w[a * 32 + b];
        }
#pragma unroll
        for (int b = 0; b < 8; ++b) outp[(qq * 8 + b) * 75 + vk] = acc[b];
    }
}

extern "C" void kernel_launch(void* const* d_in, const int* in_sizes, int n_in,
                              void* d_out, int out_size, void* d_ws, size_t ws_size,
                              hipStream_t stream) {
    const float* x1 = (const float*)d_in[0];
    const float* x2 = (const float*)d_in[1];
    const float* W1s = (const float*)d_in[2];
    const float* W2s = (const float*)d_in[3];
    const float* Wouts = (const float*)d_in[4];
    const float* Y = (const float*)d_in[5];
    const float* qw = (const float*)d_in[6];
    float* out = (float*)d_out;

    f16* A1buf = (f16*)d_ws;
    f16* B2buf = (f16*)((char*)d_ws + 129024);

    if (ws_size >= 258048) {
        vg_prep<<<NGB32, 64, 0, stream>>>(Y, qw, A1buf, B2buf);
        vg_main<true><<<1536, 256, 0, stream>>>(x1, x2, W1s, W2s, Wouts, Y, qw,
                                                A1buf, B2buf, out);
    } else {
        vg_main<false><<<1536, 256, 0, stream>>>(x1, x2, W1s, W2s, Wouts, Y, qw,
                                                 nullptr, nullptr, out);
    }
}

// Round 13
// 78.292 us; speedup vs baseline: 4.7234x; 4.7234x over previous
//
#include <hip/hip_runtime.h>

#define G_TOT 2016
#define NGB32 63
#define HSTR 40   // hbuf row stride in f16 (80B): fragment-contiguous, 2-way banks
#define CSTR 33   // cob row stride (f32)

typedef _Float16 f16;
typedef __attribute__((ext_vector_type(2))) _Float16 v2h;
typedef __attribute__((ext_vector_type(8))) _Float16 v8h;
typedef __attribute__((ext_vector_type(4))) float v4f;

__device__ __forceinline__ v2h pkrtz(float a, float b) {
    return __builtin_bit_cast(v2h, __builtin_amdgcn_cvt_pkrtz(a, b));
}

// ---------------------------------------------------------------------------
// Prep: gather Y into x32-MFMA-fragment-ordered f16 tables (per 32-g block).
// ---------------------------------------------------------------------------
__global__ void vg_prep(const float* __restrict__ Y, const float* __restrict__ qw,
                        f16* __restrict__ A1buf, f16* __restrict__ B2buf) {
    const int gb = blockIdx.x;
    const int lane = threadIdx.x & 63;
    const int lhi = lane >> 4, llo = lane & 15;
#pragma unroll
    for (int gh = 0; gh < 2; ++gh) {
        const int g = gb * 32 + gh * 16 + llo;
#pragma unroll
        for (int j = 0; j < 8; ++j) {
            const int k = (j < 4) ? (lhi * 4 + j) : (16 + lhi * 4 + (j - 4));
            const float v = (k < 25) ? Y[k * G_TOT + g] : 0.0f;
            A1buf[((gb * 2 + gh) * 64 + lane) * 8 + j] = (f16)v;
        }
    }
#pragma unroll
    for (int t = 0; t < 2; ++t) {
        const int k = t * 16 + llo;
#pragma unroll
        for (int j = 0; j < 8; ++j) {
            const int g = gb * 32 + ((j < 4) ? (lhi * 4 + j) : (16 + lhi * 4 + (j - 4)));
            const float v = (k < 25) ? Y[k * G_TOT + g] * qw[g] : 0.0f;
            B2buf[((gb * 2 + t) * 64 + lane) * 8 + j] = (f16)v;
        }
    }
}

// ---------------------------------------------------------------------------
// Main fused kernel: 256 threads per (n, parity); waves = (h = c-half, q = g-half).
// Main loop: software-pipelined at gh-half granularity. Stage = 6-MFMA cluster
// into a 24-reg ag set (ping/pong agE/agO -> only 48 pipeline regs, fits the
// (256,3) 170-reg cap; R12's body-level version needed ~200 and spilled).
// Per phase: issue MFMA1(next half) -> sched_barrier(0) -> cross(prev half).
// ---------------------------------------------------------------------------
template <bool USE_WS>
__global__ __launch_bounds__(256, 3)
void vg_main(const float* __restrict__ x1, const float* __restrict__ x2,
             const float* __restrict__ W1s, const float* __restrict__ W2s,
             const float* __restrict__ Wouts, const float* __restrict__ Y,
             const float* __restrict__ qw,
             const f16* __restrict__ A1buf, const f16* __restrict__ B2buf,
             float* __restrict__ out) {
    __shared__ __align__(16) char smem[15360];
    f16* hb = (f16*)smem;        // [2][96][HSTR] f16, fragment layout (phase 0)
    float* cob = (float*)smem;   // [96][CSTR] f32 (reduce/epilogue; aliased)

    const int bid = blockIdx.x;
    const int n = bid / 3, p = bid % 3;
    const int tid = threadIdx.x;
    const int wid = tid >> 6;
    const int h = wid & 1;       // c-half owned (main loop)
    const int q = wid >> 1;      // g-split (main loop)
    const int lane = tid & 63;
    const int lhi = lane >> 4, llo = lane & 15;

    const v4f zero4 = {0.0f, 0.0f, 0.0f, 0.0f};

    // ---- phase 0a: zero hb (padding slots must be 0)
    for (int i = tid; i < 3840; i += 256) ((float*)smem)[i] = 0.0f;
    __syncthreads();

    // ---- phase 0b (MFMA, all 4 waves): wave (s, ct) computes its quarter.
    {
        const int s = wid & 1, ct = wid >> 1;
        const float* xs = (s ? x2 : x1) + n * 2400;
        const float* Wp = (s ? W2s : W1s) + p * 5120;
        v8h bf[5];
#pragma unroll
        for (int l = 0; l < 5; ++l)
#pragma unroll
            for (int j = 0; j < 8; ++j) {
                const int f = (j < 4) ? (lhi * 4 + j) : (16 + lhi * 4 + (j - 4));
                bf[l][j] = (f16)Wp[l * 1024 + f * 32 + ct * 16 + llo];
            }
        f16* hbs = hb + s * 96 * HSTR;
#pragma unroll
        for (int vt = 0; vt < 5; ++vt) {
            v8h af;
            const int vkb = vt * 16 + llo;
#pragma unroll
            for (int j = 0; j < 8; ++j) {
                const int f = (j < 4) ? (lhi * 4 + j) : (16 + lhi * 4 + (j - 4));
                af[j] = (vkb < 75) ? (f16)xs[f * 75 + vkb] : (f16)0.0f;
            }
            v4f D[5];
#pragma unroll
            for (int l = 0; l < 5; ++l)
                D[l] = __builtin_amdgcn_mfma_f32_16x16x32_f16(af, bf[l], zero4, 0, 0, 0);
#pragma unroll
            for (int j = 0; j < 4; ++j) {
                const int vk = vt * 16 + lhi * 4 + j;
                if (vk < 75) {
                    const int v = (vk >= 50) ? 2 : ((vk >= 25) ? 1 : 0);
                    const int k = vk - v * 25;
                    const float val = (k < 1) ? D[0][j]
                                    : (k < 4) ? D[1][j]
                                    : (k < 9) ? D[2][j]
                                    : (k < 16) ? D[3][j]
                                    : D[4][j];
                    const int ks = (k < 16) ? ((k >> 2) * 8 + (k & 3))
                                           : (((k - 16) >> 2) * 8 + 4 + ((k - 16) & 3));
                    hbs[(v * 32 + ct * 16 + llo) * HSTR + ks] = (f16)val;
                }
            }
        }
    }
    __syncthreads();

    // ---- hoist this wave's h fragments: tiles Rn = 2*vc + h (6 x v8h = 24 VGPR)
    v8h hfr[2][3];
    {
        const f16* hfb = &hb[llo * HSTR + lhi * 8];
#pragma unroll
        for (int s = 0; s < 2; ++s)
#pragma unroll
            for (int vc = 0; vc < 3; ++vc)
                hfr[s][vc] = *(const v8h*)(hfb + (s * 96 + (2 * vc + h) * 16) * HSTR);
    }

    v4f coacc[3][2];
#pragma unroll
    for (int vc = 0; vc < 3; ++vc)
#pragma unroll
        for (int t = 0; t < 2; ++t) coacc[vc][t] = zero4;

    union A2U { v2h p[4]; v8h v; };

    // one gh-half MFMA1 cluster: 6 MFMAs into ag[2][3] (24 regs)
    auto mfma1h = [&](const v8h& a1, v4f (&ag)[2][3]) {
#pragma unroll
        for (int s = 0; s < 2; ++s)
#pragma unroll
            for (int vc = 0; vc < 3; ++vc)
                ag[s][vc] = __builtin_amdgcn_mfma_f32_16x16x32_f16(
                    a1, hfr[s][vc], zero4, 0, 0, 0);
    };

    // packed-f16 cross for one gh-half into a2u slots gh*2+{0,1}
    auto crossh = [&](const v4f (&ag)[2][3], A2U (&a2u)[3], int gh) {
        v2h g1[3][2], g2[3][2];
#pragma unroll
        for (int vc = 0; vc < 3; ++vc) {
            g1[vc][0] = pkrtz(ag[0][vc][0], ag[0][vc][1]);
            g1[vc][1] = pkrtz(ag[0][vc][2], ag[0][vc][3]);
            g2[vc][0] = pkrtz(ag[1][vc][0], ag[1][vc][1]);
            g2[vc][1] = pkrtz(ag[1][vc][2], ag[1][vc][3]);
        }
#pragma unroll
        for (int jp = 0; jp < 2; ++jp) {
            a2u[0].p[gh * 2 + jp] = g1[1][jp] * g2[2][jp] - g1[2][jp] * g2[1][jp];
            a2u[1].p[gh * 2 + jp] = g1[2][jp] * g2[0][jp] - g1[0][jp] * g2[2][jp];
            a2u[2].p[gh * 2 + jp] = g1[0][jp] * g2[1][jp] - g1[1][jp] * g2[0][jp];
        }
    };

    auto mfma2 = [&](A2U (&a2u)[3], const v8h& b2lo, const v8h& b2hi) {
#pragma unroll
        for (int vc = 0; vc < 3; ++vc) {
            coacc[vc][0] = __builtin_amdgcn_mfma_f32_16x16x32_f16(a2u[vc].v, b2lo, coacc[vc][0], 0, 0, 0);
            coacc[vc][1] = __builtin_amdgcn_mfma_f32_16x16x32_f16(a2u[vc].v, b2hi, coacc[vc][1], 0, 0, 0);
        }
    };

    // ---- main loop: gh-half software pipeline over bodies (gb = q + 2b)
    if constexpr (USE_WS) {
        const v8h* base_a = (const v8h*)A1buf + lane;
        const v8h* base_b = (const v8h*)B2buf + lane;
        const int iters = (NGB32 - q + 1) >> 1;        // q=0:32, q=1:31
        auto offA = [&](int b) { return (b < iters) ? (q + 2 * b) * 128 : q * 128; };

        v8h FAe_lo, FAe_hi, FAo_lo, FAo_hi, FBe_lo, FBe_hi, FBo_lo, FBo_hi;
        v4f agE[2][3], agO[2][3];
        A2U a2u[3];

        // prologue: frags for bodies 0,1; issue (b0, gh0)
        { const v8h* pa = base_a + offA(0); FAe_lo = pa[0]; FAe_hi = pa[64]; }
        { const v8h* pb = base_b + offA(0); FBe_lo = pb[0]; FBe_hi = pb[64]; }
        { const v8h* pa = base_a + offA(1); FAo_lo = pa[0]; FAo_hi = pa[64]; }
        { const v8h* pb = base_b + offA(1); FBo_lo = pb[0]; FBo_hi = pb[64]; }
        mfma1h(FAe_lo, agE);

        const int npairs = iters >> 1;
        for (int k = 0; k < npairs; ++k) {
            // body 2k
            mfma1h(FAe_hi, agO);                       // (2k, gh1)
            __builtin_amdgcn_sched_barrier(0);
            crossh(agE, a2u, 0);                       // (2k, gh0)
            { const v8h* pa = base_a + offA(2 * k + 2); FAe_lo = pa[0]; FAe_hi = pa[64]; }
            mfma1h(FAo_lo, agE);                       // (2k+1, gh0)
            __builtin_amdgcn_sched_barrier(0);
            crossh(agO, a2u, 1);                       // (2k, gh1)
            mfma2(a2u, FBe_lo, FBe_hi);                // body 2k done
            { const v8h* pb = base_b + offA(2 * k + 2); FBe_lo = pb[0]; FBe_hi = pb[64]; }
            // body 2k+1
            mfma1h(FAo_hi, agO);                       // (2k+1, gh1)
            __builtin_amdgcn_sched_barrier(0);
            crossh(agE, a2u, 0);                       // (2k+1, gh0)
            { const v8h* pa = base_a + offA(2 * k + 3); FAo_lo = pa[0]; FAo_hi = pa[64]; }
            mfma1h(FAe_lo, agE);                       // (2k+2, gh0) [dead if k last & even iters]
            __builtin_amdgcn_sched_barrier(0);
            crossh(agO, a2u, 1);                       // (2k+1, gh1)
            mfma2(a2u, FBo_lo, FBo_hi);                // body 2k+1 done
            { const v8h* pb = base_b + offA(2 * k + 3); FBo_lo = pb[0]; FBo_hi = pb[64]; }
        }
        if (iters & 1) {                               // last even-indexed body
            mfma1h(FAe_hi, agO);
            crossh(agE, a2u, 0);
            crossh(agO, a2u, 1);
            mfma2(a2u, FBe_lo, FBe_hi);
        }
    } else {
        for (int gb = q; gb < NGB32; gb += 2) {
            v8h b20, b21, a10, a11;
#pragma unroll
            for (int j = 0; j < 8; ++j) {
                const int gg = gb * 32 + ((j < 4) ? (lhi * 4 + j) : (16 + lhi * 4 + (j - 4)));
                const float qg = qw[gg];
                b20[j] = (f16)(Y[llo * G_TOT + gg] * qg);
                const int k1 = 16 + llo;
                b21[j] = (f16)((k1 < 25) ? Y[k1 * G_TOT + gg] * qg : 0.0f);
                const int k = (j < 4) ? (lhi * 4 + j) : (16 + lhi * 4 + (j - 4));
                a10[j] = (f16)((k < 25) ? Y[k * G_TOT + gb * 32 + llo] : 0.0f);
                a11[j] = (f16)((k < 25) ? Y[k * G_TOT + gb * 32 + 16 + llo] : 0.0f);
            }
            v4f agA[2][3], agB[2][3];
            A2U a2u[3];
            mfma1h(a10, agA);
            mfma1h(a11, agB);
            crossh(agA, a2u, 0);
            crossh(agB, a2u, 1);
            mfma2(a2u, b20, b21);
        }
    }

    // ---- CO: q=0 writes, q=1 accumulates (waves own disjoint rows across h)
    __syncthreads();
    if (q == 0) {
#pragma unroll
        for (int vc = 0; vc < 3; ++vc)
#pragma unroll
            for (int t = 0; t < 2; ++t)
#pragma unroll
                for (int j = 0; j < 4; ++j) {
                    const int row = (2 * vc + h) * 16 + lhi * 4 + j;
                    cob[row * CSTR + t * 16 + llo] = coacc[vc][t][j];
                }
    }
    __syncthreads();
    if (q == 1) {
#pragma unroll
        for (int vc = 0; vc < 3; ++vc)
#pragma unroll
            for (int t = 0; t < 2; ++t)
#pragma unroll
                for (int j = 0; j < 4; ++j) {
                    const int row = (2 * vc + h) * 16 + lhi * 4 + j;
                    cob[row * CSTR + t * 16 + llo] += coacc[vc][t][j];
                }
    }
    __syncthreads();

    // ---- epilogue: out[n, p*32+b, v, k] = sum_a co[v*32+a][k] * Wout[p,l_k,a,b]
    const float* Wop = Wouts + p * 5120;
    float* outp = out + (n * 96 + p * 32) * 75;
    for (int idx = tid; idx < 300; idx += 256) {
        const int vk = idx % 75, qq = idx / 75;
        const int v = vk / 25, k = vk - v * 25;
        const int l = (k >= 16) ? 4 : (k >= 9) ? 3 : (k >= 4) ? 2 : (k >= 1) ? 1 : 0;
        const float* w = Wop + l * 1024 + qq * 8;
        float acc[8];
#pragma unroll
        for (int b = 0; b < 8; ++b) acc[b] = 0.0f;
        for (int a = 0; a < 32; ++a) {
            const float cv = cob[(v * 32 + a) * CSTR + k];
#pragma unroll
            for (int b = 0; b < 8; ++b) acc[b] += cv * w[a * 32 + b];
        }
#pragma unroll
        for (int b = 0; b < 8; ++b) outp[(qq * 8 + b) * 75 + vk] = acc[b];
    }
}

extern "C" void kernel_launch(void* const* d_in, const int* in_sizes, int n_in,
                              void* d_out, int out_size, void* d_ws, size_t ws_size,
                              hipStream_t stream) {
    const float* x1 = (const float*)d_in[0];
    const float* x2 = (const float*)d_in[1];
    const float* W1s = (const float*)d_in[2];
    const float* W2s = (const float*)d_in[3];
    const float* Wouts = (const float*)d_in[4];
    const float* Y = (const float*)d_in[5];
    const float* qw = (const float*)d_in[6];
    float* out = (float*)d_out;

    f16* A1buf = (f16*)d_ws;
    f16* B2buf = (f16*)((char*)d_ws + 129024);

    if (ws_size >= 258048) {
        vg_prep<<<NGB32, 64, 0, stream>>>(Y, qw, A1buf, B2buf);
        vg_main<true><<<1536, 256, 0, stream>>>(x1, x2, W1s, W2s, Wouts, Y, qw,
                                                A1buf, B2buf, out);
    } else {
        vg_main<false><<<1536, 256, 0, stream>>>(x1, x2, W1s, W2s, Wouts, Y, qw,
                                                 nullptr, nullptr, out);
    }
}

// Round 14
// 72.718 us; speedup vs baseline: 5.0854x; 1.0766x over previous
//
#include <hip/hip_runtime.h>

#define G_TOT 2016
#define NGB32 63
#define HSTR 40   // hbuf row stride in f16 (80B): fragment-contiguous, 2-way banks
#define CSTR 33   // cob row stride (f32)

typedef _Float16 f16;
typedef __attribute__((ext_vector_type(2))) _Float16 v2h;
typedef __attribute__((ext_vector_type(8))) _Float16 v8h;
typedef __attribute__((ext_vector_type(4))) float v4f;

__device__ __forceinline__ v2h pkrtz(float a, float b) {
    return __builtin_bit_cast(v2h, __builtin_amdgcn_cvt_pkrtz(a, b));
}

// ---------------------------------------------------------------------------
// Prep: gather Y into x32-MFMA-fragment-ordered f16 tables (per 32-g block).
// ---------------------------------------------------------------------------
__global__ void vg_prep(const float* __restrict__ Y, const float* __restrict__ qw,
                        f16* __restrict__ A1buf, f16* __restrict__ B2buf) {
    const int gb = blockIdx.x;
    const int lane = threadIdx.x & 63;
    const int lhi = lane >> 4, llo = lane & 15;
#pragma unroll
    for (int gh = 0; gh < 2; ++gh) {
        const int g = gb * 32 + gh * 16 + llo;
#pragma unroll
        for (int j = 0; j < 8; ++j) {
            const int k = (j < 4) ? (lhi * 4 + j) : (16 + lhi * 4 + (j - 4));
            const float v = (k < 25) ? Y[k * G_TOT + g] : 0.0f;
            A1buf[((gb * 2 + gh) * 64 + lane) * 8 + j] = (f16)v;
        }
    }
#pragma unroll
    for (int t = 0; t < 2; ++t) {
        const int k = t * 16 + llo;
#pragma unroll
        for (int j = 0; j < 8; ++j) {
            const int g = gb * 32 + ((j < 4) ? (lhi * 4 + j) : (16 + lhi * 4 + (j - 4)));
            const float v = (k < 25) ? Y[k * G_TOT + g] * qw[g] : 0.0f;
            B2buf[((gb * 2 + t) * 64 + lane) * 8 + j] = (f16)v;
        }
    }
}

// ---------------------------------------------------------------------------
// Main fused kernel: 256 threads per (n, parity); waves = (h = c-half, q = g-half).
// Main loop: R13's gh-half software pipeline (equal-best with R10).
// EPILOGUE is now MFMA-based: per (v=wid<3, l): out_l[b][k] = W_l^T x co is an
// M=32 x N=kw x K=32 GEMM -> 10 MFMAs/wave replaces the scalar gather storm
// (~64 gathered VMEM + 256 FMA per idx-iteration) that contended on the TA pipe.
// ---------------------------------------------------------------------------
template <bool USE_WS>
__global__ __launch_bounds__(256, 3)
void vg_main(const float* __restrict__ x1, const float* __restrict__ x2,
             const float* __restrict__ W1s, const float* __restrict__ W2s,
             const float* __restrict__ Wouts, const float* __restrict__ Y,
             const float* __restrict__ qw,
             const f16* __restrict__ A1buf, const f16* __restrict__ B2buf,
             float* __restrict__ out) {
    __shared__ __align__(16) char smem[15360];
    f16* hb = (f16*)smem;        // [2][96][HSTR] f16, fragment layout (phase 0)
    float* cob = (float*)smem;   // [96][CSTR] f32 (reduce/epilogue; aliased)

    const int bid = blockIdx.x;
    const int n = bid / 3, p = bid % 3;
    const int tid = threadIdx.x;
    const int wid = tid >> 6;
    const int h = wid & 1;       // c-half owned (main loop)
    const int q = wid >> 1;      // g-split (main loop)
    const int lane = tid & 63;
    const int lhi = lane >> 4, llo = lane & 15;

    const v4f zero4 = {0.0f, 0.0f, 0.0f, 0.0f};

    // ---- phase 0a: zero hb (padding slots must be 0)
    for (int i = tid; i < 3840; i += 256) ((float*)smem)[i] = 0.0f;
    __syncthreads();

    // ---- phase 0b (MFMA, all 4 waves): wave (s, ct) computes its quarter.
    {
        const int s = wid & 1, ct = wid >> 1;
        const float* xs = (s ? x2 : x1) + n * 2400;
        const float* Wp = (s ? W2s : W1s) + p * 5120;
        v8h bf[5];
#pragma unroll
        for (int l = 0; l < 5; ++l)
#pragma unroll
            for (int j = 0; j < 8; ++j) {
                const int f = (j < 4) ? (lhi * 4 + j) : (16 + lhi * 4 + (j - 4));
                bf[l][j] = (f16)Wp[l * 1024 + f * 32 + ct * 16 + llo];
            }
        f16* hbs = hb + s * 96 * HSTR;
#pragma unroll
        for (int vt = 0; vt < 5; ++vt) {
            v8h af;
            const int vkb = vt * 16 + llo;
#pragma unroll
            for (int j = 0; j < 8; ++j) {
                const int f = (j < 4) ? (lhi * 4 + j) : (16 + lhi * 4 + (j - 4));
                af[j] = (vkb < 75) ? (f16)xs[f * 75 + vkb] : (f16)0.0f;
            }
            v4f D[5];
#pragma unroll
            for (int l = 0; l < 5; ++l)
                D[l] = __builtin_amdgcn_mfma_f32_16x16x32_f16(af, bf[l], zero4, 0, 0, 0);
#pragma unroll
            for (int j = 0; j < 4; ++j) {
                const int vk = vt * 16 + lhi * 4 + j;
                if (vk < 75) {
                    const int v = (vk >= 50) ? 2 : ((vk >= 25) ? 1 : 0);
                    const int k = vk - v * 25;
                    const float val = (k < 1) ? D[0][j]
                                    : (k < 4) ? D[1][j]
                                    : (k < 9) ? D[2][j]
                                    : (k < 16) ? D[3][j]
                                    : D[4][j];
                    const int ks = (k < 16) ? ((k >> 2) * 8 + (k & 3))
                                           : (((k - 16) >> 2) * 8 + 4 + ((k - 16) & 3));
                    hbs[(v * 32 + ct * 16 + llo) * HSTR + ks] = (f16)val;
                }
            }
        }
    }
    __syncthreads();

    // ---- hoist this wave's h fragments: tiles Rn = 2*vc + h (6 x v8h = 24 VGPR)
    v8h hfr[2][3];
    {
        const f16* hfb = &hb[llo * HSTR + lhi * 8];
#pragma unroll
        for (int s = 0; s < 2; ++s)
#pragma unroll
            for (int vc = 0; vc < 3; ++vc)
                hfr[s][vc] = *(const v8h*)(hfb + (s * 96 + (2 * vc + h) * 16) * HSTR);
    }

    v4f coacc[3][2];
#pragma unroll
    for (int vc = 0; vc < 3; ++vc)
#pragma unroll
        for (int t = 0; t < 2; ++t) coacc[vc][t] = zero4;

    union A2U { v2h p[4]; v8h v; };

    // one gh-half MFMA1 cluster: 6 MFMAs into ag[2][3] (24 regs)
    auto mfma1h = [&](const v8h& a1, v4f (&ag)[2][3]) {
#pragma unroll
        for (int s = 0; s < 2; ++s)
#pragma unroll
            for (int vc = 0; vc < 3; ++vc)
                ag[s][vc] = __builtin_amdgcn_mfma_f32_16x16x32_f16(
                    a1, hfr[s][vc], zero4, 0, 0, 0);
    };

    // packed-f16 cross for one gh-half into a2u slots gh*2+{0,1}
    auto crossh = [&](const v4f (&ag)[2][3], A2U (&a2u)[3], int gh) {
        v2h g1[3][2], g2[3][2];
#pragma unroll
        for (int vc = 0; vc < 3; ++vc) {
            g1[vc][0] = pkrtz(ag[0][vc][0], ag[0][vc][1]);
            g1[vc][1] = pkrtz(ag[0][vc][2], ag[0][vc][3]);
            g2[vc][0] = pkrtz(ag[1][vc][0], ag[1][vc][1]);
            g2[vc][1] = pkrtz(ag[1][vc][2], ag[1][vc][3]);
        }
#pragma unroll
        for (int jp = 0; jp < 2; ++jp) {
            a2u[0].p[gh * 2 + jp] = g1[1][jp] * g2[2][jp] - g1[2][jp] * g2[1][jp];
            a2u[1].p[gh * 2 + jp] = g1[2][jp] * g2[0][jp] - g1[0][jp] * g2[2][jp];
            a2u[2].p[gh * 2 + jp] = g1[0][jp] * g2[1][jp] - g1[1][jp] * g2[0][jp];
        }
    };

    auto mfma2 = [&](A2U (&a2u)[3], const v8h& b2lo, const v8h& b2hi) {
#pragma unroll
        for (int vc = 0; vc < 3; ++vc) {
            coacc[vc][0] = __builtin_amdgcn_mfma_f32_16x16x32_f16(a2u[vc].v, b2lo, coacc[vc][0], 0, 0, 0);
            coacc[vc][1] = __builtin_amdgcn_mfma_f32_16x16x32_f16(a2u[vc].v, b2hi, coacc[vc][1], 0, 0, 0);
        }
    };

    // ---- main loop: gh-half software pipeline over bodies (gb = q + 2b)
    if constexpr (USE_WS) {
        const v8h* base_a = (const v8h*)A1buf + lane;
        const v8h* base_b = (const v8h*)B2buf + lane;
        const int iters = (NGB32 - q + 1) >> 1;        // q=0:32, q=1:31
        auto offA = [&](int b) { return (b < iters) ? (q + 2 * b) * 128 : q * 128; };

        v8h FAe_lo, FAe_hi, FAo_lo, FAo_hi, FBe_lo, FBe_hi, FBo_lo, FBo_hi;
        v4f agE[2][3], agO[2][3];
        A2U a2u[3];

        { const v8h* pa = base_a + offA(0); FAe_lo = pa[0]; FAe_hi = pa[64]; }
        { const v8h* pb = base_b + offA(0); FBe_lo = pb[0]; FBe_hi = pb[64]; }
        { const v8h* pa = base_a + offA(1); FAo_lo = pa[0]; FAo_hi = pa[64]; }
        { const v8h* pb = base_b + offA(1); FBo_lo = pb[0]; FBo_hi = pb[64]; }
        mfma1h(FAe_lo, agE);

        const int npairs = iters >> 1;
        for (int k = 0; k < npairs; ++k) {
            mfma1h(FAe_hi, agO);
            __builtin_amdgcn_sched_barrier(0);
            crossh(agE, a2u, 0);
            { const v8h* pa = base_a + offA(2 * k + 2); FAe_lo = pa[0]; FAe_hi = pa[64]; }
            mfma1h(FAo_lo, agE);
            __builtin_amdgcn_sched_barrier(0);
            crossh(agO, a2u, 1);
            mfma2(a2u, FBe_lo, FBe_hi);
            { const v8h* pb = base_b + offA(2 * k + 2); FBe_lo = pb[0]; FBe_hi = pb[64]; }
            mfma1h(FAo_hi, agO);
            __builtin_amdgcn_sched_barrier(0);
            crossh(agE, a2u, 0);
            { const v8h* pa = base_a + offA(2 * k + 3); FAo_lo = pa[0]; FAo_hi = pa[64]; }
            mfma1h(FAe_lo, agE);
            __builtin_amdgcn_sched_barrier(0);
            crossh(agO, a2u, 1);
            mfma2(a2u, FBo_lo, FBo_hi);
            { const v8h* pb = base_b + offA(2 * k + 3); FBo_lo = pb[0]; FBo_hi = pb[64]; }
        }
        if (iters & 1) {
            mfma1h(FAe_hi, agO);
            crossh(agE, a2u, 0);
            crossh(agO, a2u, 1);
            mfma2(a2u, FBe_lo, FBe_hi);
        }
    } else {
        for (int gb = q; gb < NGB32; gb += 2) {
            v8h b20, b21, a10, a11;
#pragma unroll
            for (int j = 0; j < 8; ++j) {
                const int gg = gb * 32 + ((j < 4) ? (lhi * 4 + j) : (16 + lhi * 4 + (j - 4)));
                const float qg = qw[gg];
                b20[j] = (f16)(Y[llo * G_TOT + gg] * qg);
                const int k1 = 16 + llo;
                b21[j] = (f16)((k1 < 25) ? Y[k1 * G_TOT + gg] * qg : 0.0f);
                const int k = (j < 4) ? (lhi * 4 + j) : (16 + lhi * 4 + (j - 4));
                a10[j] = (f16)((k < 25) ? Y[k * G_TOT + gb * 32 + llo] : 0.0f);
                a11[j] = (f16)((k < 25) ? Y[k * G_TOT + gb * 32 + 16 + llo] : 0.0f);
            }
            v4f agA[2][3], agB[2][3];
            A2U a2u[3];
            mfma1h(a10, agA);
            mfma1h(a11, agB);
            crossh(agA, a2u, 0);
            crossh(agB, a2u, 1);
            mfma2(a2u, b20, b21);
        }
    }

    // ---- CO: q=0 writes, q=1 accumulates (waves own disjoint rows across h)
    __syncthreads();
    if (q == 0) {
#pragma unroll
        for (int vc = 0; vc < 3; ++vc)
#pragma unroll
            for (int t = 0; t < 2; ++t)
#pragma unroll
                for (int j = 0; j < 4; ++j) {
                    const int row = (2 * vc + h) * 16 + lhi * 4 + j;
                    cob[row * CSTR + t * 16 + llo] = coacc[vc][t][j];
                }
    }
    __syncthreads();
    if (q == 1) {
#pragma unroll
        for (int vc = 0; vc < 3; ++vc)
#pragma unroll
            for (int t = 0; t < 2; ++t)
#pragma unroll
                for (int j = 0; j < 4; ++j) {
                    const int row = (2 * vc + h) * 16 + lhi * 4 + j;
                    cob[row * CSTR + t * 16 + llo] += coacc[vc][t][j];
                }
    }
    __syncthreads();

    // ---- epilogue (MFMA): wave v=wid<3 computes out[b][v,k] = sum_a W_l[a][b]*co[a][k]
    // per l: A-frag = W_l^T[b][a] (m=b, k=a), B-frag = co[a][k0+llo] (n=k_local).
    if (wid < 3) {
        const int v = wid;
        const float* Wop = Wouts + p * 5120;
        float* outp = out + (n * 96 + p * 32) * 75 + v * 25;
        const int k0s[5] = {0, 1, 4, 9, 16};
        const int kws[5] = {1, 3, 5, 7, 9};
#pragma unroll
        for (int l = 0; l < 5; ++l) {
            const int k0 = k0s[l], kw = kws[l];
            // B-frag: elems j -> a = lhi*4+j (+16), col n = llo (k_local)
            v8h Bf;
            const int kk = (llo < kw) ? (k0 + llo) : k0;   // clamp in-range
#pragma unroll
            for (int j = 0; j < 8; ++j) {
                const int a = (j < 4) ? (lhi * 4 + j) : (16 + lhi * 4 + (j - 4));
                const float bv = (llo < kw) ? cob[(v * 32 + a) * CSTR + kk] : 0.0f;
                Bf[j] = (f16)bv;
            }
#pragma unroll
            for (int bt = 0; bt < 2; ++bt) {
                // A-frag: m = b = bt*16+llo, k = a; A[b][a] = W_l[a][b]
                v8h Af;
#pragma unroll
                for (int j = 0; j < 8; ++j) {
                    const int a = (j < 4) ? (lhi * 4 + j) : (16 + lhi * 4 + (j - 4));
                    Af[j] = (f16)Wop[l * 1024 + a * 32 + bt * 16 + llo];
                }
                v4f D = __builtin_amdgcn_mfma_f32_16x16x32_f16(Af, Bf, zero4, 0, 0, 0);
                // D: col = llo = k_local, row = b = bt*16 + lhi*4 + jj
                if (llo < kw) {
#pragma unroll
                    for (int jj = 0; jj < 4; ++jj)
                        outp[(bt * 16 + lhi * 4 + jj) * 75 + k0 + llo] = D[jj];
                }
            }
        }
    }
}

extern "C" void kernel_launch(void* const* d_in, const int* in_sizes, int n_in,
                              void* d_out, int out_size, void* d_ws, size_t ws_size,
                              hipStream_t stream) {
    const float* x1 = (const float*)d_in[0];
    const float* x2 = (const float*)d_in[1];
    const float* W1s = (const float*)d_in[2];
    const float* W2s = (const float*)d_in[3];
    const float* Wouts = (const float*)d_in[4];
    const float* Y = (const float*)d_in[5];
    const float* qw = (const float*)d_in[6];
    float* out = (float*)d_out;

    f16* A1buf = (f16*)d_ws;
    f16* B2buf = (f16*)((char*)d_ws + 129024);

    if (ws_size >= 258048) {
        vg_prep<<<NGB32, 64, 0, stream>>>(Y, qw, A1buf, B2buf);
        vg_main<true><<<1536, 256, 0, stream>>>(x1, x2, W1s, W2s, Wouts, Y, qw,
                                                A1buf, B2buf, out);
    } else {
        vg_main<false><<<1536, 256, 0, stream>>>(x1, x2, W1s, W2s, Wouts, Y, qw,
                                                 nullptr, nullptr, out);
    }
}